// Round 9
// baseline (597.375 us; speedup 1.0000x reference)
//
#include <hip/hip_runtime.h>

// Swin window attention, fully fused, persistent blocks (1 block/CU, 256
// blocks, 16-batch loop per block).
//
// R7 change (recovering from R6's 269us regression; R5 = 162us is the base):
// R6 post-mortem: wave-role specialization halved the wave count on the
// LATENCY-critical attention (8 consumer waves x 2 serial head-tasks each
// doubled the softmax critical path; barriers forced sum-of-maxes). Fix:
// keep attn on ALL 16 waves (serial depth 1, as R5) and overlap across TIME:
//   chunk A: attn(b) [all waves] + store pass(b-1) + issue x(b+1) loads
//   bar1
//   chunk B: out-proj(b) + QKV(b+1) from x registers   [both pure MFMA]
//   bar2
// QKV's standalone phase disappears into proj's chunk (independent work
// co-hides); stores + x-load latency hide under attn; 2 barriers/iter
// (R5: 3). Since attn(b) precedes QKV(b+1) within the iteration, q/k/v are
// SINGLE-buffered. P uses per-wave scratch (same-wave lgkm-drained).
// Native bf16 casts kept from R6 (v_cvt_pk_bf16_f32, identical RNE).
// LDS 157952 B: q 17408 | k 17408 | v 18432 | Ps 16x[16][72] 36864 |
//               oa 17408 | osr f32 [64][132] 33792 | bias 16640.
// Hazard audit (every cross-wave pair crosses exactly one barrier):
//   q/k/v: written chunk B(b) -> read chunk A(b+1): bar2. read A(b) vs
//     write B(b): bar1. | oa: write A(b) -> read B(b): bar1; next write
//     A(b+1) after B(b) reads: bar2. | osr: write B(b) -> read A(b+1)
//     stores: bar2; next write B(b+1) after A(b+1) reads: bar1. | Ps:
//     same-wave only, lgkmcnt(0)+sched_barrier (rule 18). | x regs:
//     same-wave register dep across bar1 (vmcnt untouched by bar_lds).
//
// MFMA 16x16x32 bf16 fragment layouts (HW-verified per guide m89/m91/m120):
//   A[m][k]: m = lane&15, k = (lane>>4)*8 + j   (8 contiguous bf16 = 16B)
//   B[k][n]: n = lane&15, k = (lane>>4)*8 + j
//   D[m][n]: n = lane&15, m = (lane>>4)*4 + reg

typedef __bf16 bf16x8 __attribute__((ext_vector_type(8)));
typedef short  s16x8  __attribute__((ext_vector_type(8)));
typedef float  f32x4  __attribute__((ext_vector_type(4)));

static __device__ __forceinline__ unsigned short f2bf(float f) {
  __bf16 h = (__bf16)f;                      // RNE; compiler emits cvt_pk pairs
  return __builtin_bit_cast(unsigned short, h);
}
static __device__ __forceinline__ s16x8 cvt8(float4 lo, float4 hi) {
  s16x8 r;
  r[0] = (short)f2bf(lo.x); r[1] = (short)f2bf(lo.y);
  r[2] = (short)f2bf(lo.z); r[3] = (short)f2bf(lo.w);
  r[4] = (short)f2bf(hi.x); r[5] = (short)f2bf(hi.y);
  r[6] = (short)f2bf(hi.z); r[7] = (short)f2bf(hi.w);
  return r;
}
static __device__ __forceinline__ f32x4 mfma16(s16x8 a, s16x8 b, f32x4 c) {
  return __builtin_amdgcn_mfma_f32_16x16x32_bf16(
      __builtin_bit_cast(bf16x8, a), __builtin_bit_cast(bf16x8, b), c, 0, 0, 0);
}
// LDS-only barrier: orders ds ops across waves without draining vmcnt.
static __device__ __forceinline__ void bar_lds() {
  __builtin_amdgcn_sched_barrier(0);
  asm volatile("s_waitcnt lgkmcnt(0)" ::: "memory");
  __builtin_amdgcn_s_barrier();
  __builtin_amdgcn_sched_barrier(0);
}

// ---------------- prep: transpose + bf16-cast weights into workspace --------
__global__ void prep_weights(const float* __restrict__ wqkv,
                             const float* __restrict__ wout,
                             unsigned short* __restrict__ wqkvT,
                             unsigned short* __restrict__ woutT) {
  int idx = blockIdx.x * blockDim.x + threadIdx.x;
  const int total1 = 384 * 128;
  if (idx < total1) {
    int n = idx >> 7, k = idx & 127;
    wqkvT[idx] = f2bf(wqkv[k * 384 + n]);
  } else {
    int i2 = idx - total1;
    int n = i2 >> 7, k = i2 & 127;
    woutT[i2] = f2bf(wout[k * 128 + n]);
  }
}

// ---------------- LDS layout ------------------------------------------------
#define OFF_Q   0         // q  [64][136] bf16  17408
#define OFF_K   17408     // k  [64][136] bf16  17408
#define OFF_V   34816     // v  [128][72] bf16  18432  (transposed [ch][tok])
#define OFF_PS  53248     // Ps 16 x [16][72] bf16 36864 (per-wave scratch)
#define OFF_OA  90112     // oa [64][136] bf16  17408
#define OFF_OSR 107520    // osr [64][132] f32  33792
#define OFF_BI  141312    // bias [64][65] f32  16640
#define SMEM_SZ 157952

#define BATCH_STRIDE (128 * 128 * 128)   // floats per batch image

template <int KIND>   // 0=q, 1=k, 2=v
static __device__ __forceinline__ void qkv_task(
    int nt, const s16x8 (&xf)[2][4], const unsigned short* __restrict__ wqkvT,
    unsigned short* qs, unsigned short* ks_, unsigned short* vs,
    int ln15, int quad, int m_sub, int mh) {
  const int n = nt * 16 + ln15;
  const unsigned short* wp = wqkvT + n * 128 + quad * 8;
  s16x8 bfr[4];
#pragma unroll
  for (int ks = 0; ks < 4; ++ks) bfr[ks] = *(const s16x8*)(wp + ks * 32);
#pragma unroll
  for (int mi = 0; mi < 2; ++mi) {
    f32x4 acc = {0.f, 0.f, 0.f, 0.f};
#pragma unroll
    for (int ks = 0; ks < 4; ++ks) acc = mfma16(xf[mi][ks], bfr[ks], acc);
    const int tok0 = (mh * 2 + mi) * 16 + m_sub;
    if constexpr (KIND == 0) {
#pragma unroll
      for (int r = 0; r < 4; ++r) qs[(tok0 + r) * 136 + n] = f2bf(acc[r]);
    } else if constexpr (KIND == 1) {
      const int nn = n - 128;
#pragma unroll
      for (int r = 0; r < 4; ++r) ks_[(tok0 + r) * 136 + nn] = f2bf(acc[r]);
    } else {
      const int nn = n - 256;
      ushort4 pk;
      pk.x = f2bf(acc[0]); pk.y = f2bf(acc[1]);
      pk.z = f2bf(acc[2]); pk.w = f2bf(acc[3]);
      *(ushort4*)(vs + nn * 72 + tok0) = pk;   // v transposed [ch][tok]
    }
  }
}

__global__ __launch_bounds__(1024, 4)
void swin_fused(const float* __restrict__ x,
                const unsigned short* __restrict__ wqkvT,
                const unsigned short* __restrict__ woutT,
                const float* __restrict__ b_out,
                const float* __restrict__ pe,     // [15][15]
                const float* __restrict__ ulm,    // [64][64]
                const float* __restrict__ lrm,    // [64][64]
                float* __restrict__ out) {
  __shared__ __align__(16) unsigned char smem[SMEM_SZ];
  unsigned short* q_s   = (unsigned short*)(smem + OFF_Q);
  unsigned short* k_s   = (unsigned short*)(smem + OFF_K);
  unsigned short* v_s   = (unsigned short*)(smem + OFF_V);
  unsigned short* Ps    = (unsigned short*)(smem + OFF_PS) + (threadIdx.x >> 6) * 1152;
  unsigned short* oa_s  = (unsigned short*)(smem + OFF_OA);
  float*          osr_s = (float*)(smem + OFF_OSR);
  float*          bias_s = (float*)(smem + OFF_BI);

  const int tid  = threadIdx.x;
  const int lane = tid & 63;
  const int wave = tid >> 6;        // 0..15
  const int ln15 = lane & 15;
  const int quad = lane >> 4;
  const int m_sub = quad << 2;

  const int wh = blockIdx.x >> 4, ww = blockIdx.x & 15;

  // attn task (chunk A): one (h, mt) per wave -- serial depth 1.
  const int h_a  = wave >> 2;
  const int mt_a = wave & 3;
  const int tok0a = mt_a * 16 + m_sub;

  // proj task (chunk B): (n-tile, m-pair) per wave.
  const int nt_p  = wave >> 1;
  const int mtb_p = (wave & 1) * 2;

  // qkv task (chunk B): fixed mh = wave&1; nt = wave>>1 + {0,8,16}.
  const int mh = wave & 1;
  int rowoff[2];
#pragma unroll
  for (int mi = 0; mi < 2; ++mi) {
    int tok = (mh * 2 + mi) * 16 + ln15;
    int gi = ((wh << 3) + (tok >> 3) + 4) & 127;
    int gj = ((ww << 3) + (tok & 7) + 4) & 127;
    rowoff[mi] = (gi * 128 + gj) * 128;
  }

  // store pass: 2 float4 per thread, fixed addresses.
  const int tokA = tid >> 5, c4 = tid & 31;
  const int tokB = tokA + 32;
  const int giA = ((wh << 3) + (tokA >> 3) + 4) & 127;
  const int gjA = ((ww << 3) + (tokA & 7) + 4) & 127;
  const int giB = ((wh << 3) + (tokB >> 3) + 4) & 127;
  const int gjB = ((ww << 3) + (tokB & 7) + 4) & 127;
  const long offA = (long)(giA * 128 + gjA) * 128 + c4 * 4;
  const long offB = (long)(giB * 128 + gjB) * 128 + c4 * 4;
  const int lA = tokA * 132 + c4 * 4;
  const int lB = tokB * 132 + c4 * 4;

  // ---- prologue: bias table + x(0) -> regs -> QKV(0) ----
  {
    const bool has_ul = (wh == 15), has_lr = (ww == 15);
#pragma unroll
    for (int it = 0; it < 4; ++it) {
      int t = tid + it * 1024;
      int i = t >> 6, j = t & 63;
      int r0 = (j >> 3) - (i >> 3) + 7;
      int r1 = (j & 7) - (i & 7) + 7;
      float bsum = pe[r0 * 15 + r1];
      if (has_ul) bsum += ulm[t];
      if (has_lr) bsum += lrm[t];
      bias_s[i * 65 + j] = bsum;
    }
  }
  s16x8 xf[2][4];
#pragma unroll
  for (int mi = 0; mi < 2; ++mi)
#pragma unroll
    for (int ks = 0; ks < 4; ++ks) {
      const float* p = x + rowoff[mi] + ks * 32 + quad * 8;
      float4 lo = *(const float4*)p;
      float4 hi = *(const float4*)(p + 4);
      xf[mi][ks] = cvt8(lo, hi);
    }
  qkv_task<0>(wave >> 1,        xf, wqkvT, q_s, k_s, v_s, ln15, quad, m_sub, mh);
  qkv_task<1>((wave >> 1) + 8,  xf, wqkvT, q_s, k_s, v_s, ln15, quad, m_sub, mh);
  qkv_task<2>((wave >> 1) + 16, xf, wqkvT, q_s, k_s, v_s, ln15, quad, m_sub, mh);
  bar_lds();

  for (int b = 0; b < 16; ++b) {
    // ================= CHUNK A =================
    // store pass for batch b-1 (osr written in prev chunk B, crossed bar2)
    if (b > 0) {
      float* outb = out + (long)(b - 1) * BATCH_STRIDE;
      float4 o0 = *(const float4*)(osr_s + lA);
      *(float4*)(outb + offA) = o0;
      float4 o1 = *(const float4*)(osr_s + lB);
      *(float4*)(outb + offB) = o1;
    }
    // issue x(b+1) loads (held in f32 regs through attn; cvt at chunk end)
    float4 xraw[2][4][2];
    const bool pf = (b < 15);
    if (pf) {
      const float* xb = x + (long)(b + 1) * BATCH_STRIDE;
#pragma unroll
      for (int mi = 0; mi < 2; ++mi)
#pragma unroll
        for (int ks = 0; ks < 4; ++ks) {
          const float* p = xb + rowoff[mi] + ks * 32 + quad * 8;
          xraw[mi][ks][0] = *(const float4*)p;
          xraw[mi][ks][1] = *(const float4*)(p + 4);
        }
    }
    // attn(b): QK^T + bias -> register softmax -> Ps -> PV -> oa
    {
      s16x8 qf = *(const s16x8*)(q_s + (mt_a * 16 + ln15) * 136 + h_a * 32 + quad * 8);
      const float scale = 0.17677669529663687f;   // 32^-0.5
      f32x4 sv[4];
#pragma unroll
      for (int nt = 0; nt < 4; ++nt) {
        s16x8 kf = *(const s16x8*)(k_s + (nt * 16 + ln15) * 136 + h_a * 32 + quad * 8);
        f32x4 acc = {0.f, 0.f, 0.f, 0.f};
        acc = mfma16(qf, kf, acc);
        int nn = nt * 16 + ln15;
#pragma unroll
        for (int r = 0; r < 4; ++r)
          sv[nt][r] = acc[r] * scale + bias_s[(tok0a + r) * 65 + nn];
      }
      float rinv[4];
#pragma unroll
      for (int r = 0; r < 4; ++r) {
        float m0 = fmaxf(fmaxf(sv[0][r], sv[1][r]), fmaxf(sv[2][r], sv[3][r]));
        m0 = fmaxf(m0, __shfl_xor(m0, 1));
        m0 = fmaxf(m0, __shfl_xor(m0, 2));
        m0 = fmaxf(m0, __shfl_xor(m0, 4));
        m0 = fmaxf(m0, __shfl_xor(m0, 8));
        float s0 = 0.f;
#pragma unroll
        for (int nt = 0; nt < 4; ++nt) {
          float e = __expf(sv[nt][r] - m0);
          sv[nt][r] = e;
          s0 += e;
        }
        s0 += __shfl_xor(s0, 1);
        s0 += __shfl_xor(s0, 2);
        s0 += __shfl_xor(s0, 4);
        s0 += __shfl_xor(s0, 8);
        rinv[r] = 1.0f / s0;
      }
#pragma unroll
      for (int nt = 0; nt < 4; ++nt) {
        int nn = nt * 16 + ln15;
#pragma unroll
        for (int r = 0; r < 4; ++r)
          Ps[(m_sub + r) * 72 + nn] = f2bf(sv[nt][r] * rinv[r]);
      }
      // same-wave LDS RAW: wave-level drain only (rule 18 fence)
      asm volatile("s_waitcnt lgkmcnt(0)" ::: "memory");
      __builtin_amdgcn_sched_barrier(0);
      s16x8 pfr[2];
#pragma unroll
      for (int ks = 0; ks < 2; ++ks)
        pfr[ks] = *(const s16x8*)(Ps + ln15 * 72 + ks * 32 + quad * 8);
#pragma unroll
      for (int nt2 = 0; nt2 < 2; ++nt2) {
        f32x4 acc = {0.f, 0.f, 0.f, 0.f};
#pragma unroll
        for (int ks = 0; ks < 2; ++ks) {
          s16x8 vf = *(const s16x8*)(v_s + (h_a * 32 + nt2 * 16 + ln15) * 72 + ks * 32 + quad * 8);
          acc = mfma16(pfr[ks], vf, acc);
        }
        int n = h_a * 32 + nt2 * 16 + ln15;
#pragma unroll
        for (int r = 0; r < 4; ++r)
          oa_s[(tok0a + r) * 136 + n] = f2bf(acc[r]);
      }
    }
    // convert prefetched x to bf16 frags (vmcnt wait lands here, post-attn)
    if (pf) {
#pragma unroll
      for (int mi = 0; mi < 2; ++mi)
#pragma unroll
        for (int ks = 0; ks < 4; ++ks)
          xf[mi][ks] = cvt8(xraw[mi][ks][0], xraw[mi][ks][1]);
    }
    bar_lds();

    // ================= CHUNK B =================
    // out-proj(b): oa -> osr (f32)
    {
      s16x8 af[4];
      float bo[1];
      int n = nt_p * 16 + ln15;
      const unsigned short* wp = woutT + n * 128 + quad * 8;
      s16x8 bfr[4];
#pragma unroll
      for (int ks = 0; ks < 4; ++ks) bfr[ks] = *(const s16x8*)(wp + ks * 32);
      bo[0] = b_out[n];
#pragma unroll
      for (int mi = 0; mi < 2; ++mi) {
        int mt = mtb_p + mi;
#pragma unroll
        for (int ks = 0; ks < 4; ++ks)
          af[ks] = *(const s16x8*)(oa_s + (mt * 16 + ln15) * 136 + ks * 32 + quad * 8);
        f32x4 acc = {0.f, 0.f, 0.f, 0.f};
#pragma unroll
        for (int ks = 0; ks < 4; ++ks) acc = mfma16(af[ks], bfr[ks], acc);
#pragma unroll
        for (int r = 0; r < 4; ++r)
          osr_s[(mt * 16 + m_sub + r) * 132 + n] = acc[r] + bo[0];
      }
    }
    // QKV(b+1): x regs -> q/k/v LDS (single buffer; attn(b) reads done, bar1)
    if (pf) {
      qkv_task<0>(wave >> 1,        xf, wqkvT, q_s, k_s, v_s, ln15, quad, m_sub, mh);
      qkv_task<1>((wave >> 1) + 8,  xf, wqkvT, q_s, k_s, v_s, ln15, quad, m_sub, mh);
      qkv_task<2>((wave >> 1) + 16, xf, wqkvT, q_s, k_s, v_s, ln15, quad, m_sub, mh);
    }
    bar_lds();
  }

  // ---- epilogue: store batch 15 ----
  {
    float* outb = out + (long)15 * BATCH_STRIDE;
    float4 o0 = *(const float4*)(osr_s + lA);
    *(float4*)(outb + offA) = o0;
    float4 o1 = *(const float4*)(osr_s + lB);
    *(float4*)(outb + offB) = o1;
  }
}

extern "C" void kernel_launch(void* const* d_in, const int* in_sizes, int n_in,
                              void* d_out, int out_size, void* d_ws, size_t ws_size,
                              hipStream_t stream) {
  const float* x    = (const float*)d_in[0];
  const float* wqkv = (const float*)d_in[1];
  const float* wout = (const float*)d_in[2];
  const float* bout = (const float*)d_in[3];
  const float* pe   = (const float*)d_in[4];
  const float* ulm  = (const float*)d_in[5];
  const float* lrm  = (const float*)d_in[6];

  unsigned short* wqkvT = (unsigned short*)d_ws;           // 384*128 bf16
  unsigned short* woutT = wqkvT + 384 * 128;               // 128*128 bf16

  prep_weights<<<(384 * 128 + 128 * 128) / 256, 256, 0, stream>>>(wqkv, wout, wqkvT, woutT);
  swin_fused<<<256, 1024, 0, stream>>>(x, wqkvT, woutT, bout, pe, ulm, lrm,
                                       (float*)d_out);
}

// Round 10
// 473.853 us; speedup vs baseline: 1.2607x; 1.2607x over previous
//
#include <hip/hip_runtime.h>

// Swin window attention, fully fused, persistent blocks (1 block/CU, 256
// blocks, 16-batch loop per block).
//
// R8 (base = R5 @ 162us, the session best; R6/R7 structural experiments both
// regressed and are reverted):
// R7 post-mortem: holding 16 raw float4 of prefetched x across the attn
// phase spilled to scratch under the 64-VGPR cap (hbm 1.25GB, dur 449us).
// R6 post-mortem: halving the wave count on latency-critical attn doubled
// its serial depth (269us). What SURVIVES from both: bf16 register-staging
// of x (16 VGPR) is safe -- R6 showed normal traffic with xf held in regs.
// R8 = R5's exact 16-wave/3-barrier shape + register-staged x:
//   - xs LDS buffer deleted; ph1 (QKV) reads A-frags from registers.
//     Removes 24 ds_read_b128/wave/iter (~1.9us/iter of LDS issue, the
//     largest single term in R5's 10.1us/iter) + xs staging writes.
//   - x(b+1) prefetch lives ONLY inside ph5: issue 8 float4 -> proj mi=0 ->
//     cvt (frees 32 regs) -> issue 8 more -> proj mi=1 -> cvt. Peak raw
//     pressure ~72 regs, never crosses a barrier as f32.
//   - QKV(b+1) MFMAs (from xf regs) share the store chunk -> stores hide.
//   - native bf16 casts (v_cvt_pk_bf16_f32, identical RNE rounding).
//   - __launch_bounds__(1024, 2): lift the 64-VGPR cap (occupancy is
//     LDS-bound at 1 block/CU either way).
// Phase structure per batch (3 bars/iter, same count as R5):
//   ph2 attn(b) | bar1 | ph5 proj(b)+prefetch x(b+1) | bar2 |
//   ph6 store(b) + QKV(b+1) | bar3
// LDS 124160 B: q 17408 @0 | k 17408 @17408 | v 18432 @34816 |
//   S 36864 @53248 (P scratch in ph2; f32 osr[64][132]=33792 union in ph5/6)
//   | oa 17408 @90112 | bias 16640 @107520.
// Hazard audit: q/k/v written ph6(b) vs attn reads ph2(b+1): bar3; attn
//   reads ph2(b) vs writes ph6(b): bar1+bar2. oa: ph2 write -> ph5 read:
//   bar1; next write after bar3. osr: ph5 write -> ph6 read: bar2; next
//   write after bar3+bar1. S/P: same-wave only, lgkmcnt(0)+sched_barrier
//   (rule 18); osr-vs-S union: S dead from bar1(b) to bar3(b). xf: regs.
//
// MFMA 16x16x32 bf16 fragment layouts (HW-verified per guide m89/m91/m120):
//   A[m][k]: m = lane&15, k = (lane>>4)*8 + j   (8 contiguous bf16 = 16B)
//   B[k][n]: n = lane&15, k = (lane>>4)*8 + j
//   D[m][n]: n = lane&15, m = (lane>>4)*4 + reg

typedef __bf16 bf16x8 __attribute__((ext_vector_type(8)));
typedef short  s16x8  __attribute__((ext_vector_type(8)));
typedef float  f32x4  __attribute__((ext_vector_type(4)));

static __device__ __forceinline__ unsigned short f2bf(float f) {
  __bf16 h = (__bf16)f;                      // RNE; compiler emits cvt_pk pairs
  return __builtin_bit_cast(unsigned short, h);
}
static __device__ __forceinline__ s16x8 cvt8(float4 lo, float4 hi) {
  s16x8 r;
  r[0] = (short)f2bf(lo.x); r[1] = (short)f2bf(lo.y);
  r[2] = (short)f2bf(lo.z); r[3] = (short)f2bf(lo.w);
  r[4] = (short)f2bf(hi.x); r[5] = (short)f2bf(hi.y);
  r[6] = (short)f2bf(hi.z); r[7] = (short)f2bf(hi.w);
  return r;
}
static __device__ __forceinline__ f32x4 mfma16(s16x8 a, s16x8 b, f32x4 c) {
  return __builtin_amdgcn_mfma_f32_16x16x32_bf16(
      __builtin_bit_cast(bf16x8, a), __builtin_bit_cast(bf16x8, b), c, 0, 0, 0);
}
// LDS-only barrier: orders ds ops across waves without draining vmcnt.
static __device__ __forceinline__ void bar_lds() {
  __builtin_amdgcn_sched_barrier(0);
  asm volatile("s_waitcnt lgkmcnt(0)" ::: "memory");
  __builtin_amdgcn_s_barrier();
  __builtin_amdgcn_sched_barrier(0);
}

// ---------------- prep: transpose + bf16-cast weights into workspace --------
__global__ void prep_weights(const float* __restrict__ wqkv,
                             const float* __restrict__ wout,
                             unsigned short* __restrict__ wqkvT,
                             unsigned short* __restrict__ woutT) {
  int idx = blockIdx.x * blockDim.x + threadIdx.x;
  const int total1 = 384 * 128;
  if (idx < total1) {
    int n = idx >> 7, k = idx & 127;
    wqkvT[idx] = f2bf(wqkv[k * 384 + n]);
  } else {
    int i2 = idx - total1;
    int n = i2 >> 7, k = i2 & 127;
    woutT[i2] = f2bf(wout[k * 128 + n]);
  }
}

// ---------------- LDS layout ------------------------------------------------
#define OFF_Q   0         // q  [64][136] bf16  17408
#define OFF_K   17408     // k  [64][136] bf16  17408
#define OFF_V   34816     // v  [128][72] bf16  18432  (transposed [ch][tok])
#define OFF_S   53248     // S  [4][64][72] bf16 36864 (P; osr f32 union)
#define OFF_OA  90112     // oa [64][136] bf16  17408
#define OFF_BI  107520    // bias [64][65] f32  16640
#define SMEM_SZ 124160

#define BATCH_STRIDE (128 * 128 * 128)   // floats per batch image

template <int KIND>   // 0=q, 1=k, 2=v
static __device__ __forceinline__ void qkv_task(
    int nt, const s16x8 (&xf)[2][4], const unsigned short* __restrict__ wqkvT,
    unsigned short* qs, unsigned short* ks_, unsigned short* vs,
    int ln15, int quad, int m_sub, int mh) {
  const int n = nt * 16 + ln15;
  const unsigned short* wp = wqkvT + n * 128 + quad * 8;
  s16x8 bfr[4];
#pragma unroll
  for (int ks = 0; ks < 4; ++ks) bfr[ks] = *(const s16x8*)(wp + ks * 32);
#pragma unroll
  for (int mi = 0; mi < 2; ++mi) {
    f32x4 acc = {0.f, 0.f, 0.f, 0.f};
#pragma unroll
    for (int ks = 0; ks < 4; ++ks) acc = mfma16(xf[mi][ks], bfr[ks], acc);
    const int tok0 = (mh * 2 + mi) * 16 + m_sub;
    if constexpr (KIND == 0) {
#pragma unroll
      for (int r = 0; r < 4; ++r) qs[(tok0 + r) * 136 + n] = f2bf(acc[r]);
    } else if constexpr (KIND == 1) {
      const int nn = n - 128;
#pragma unroll
      for (int r = 0; r < 4; ++r) ks_[(tok0 + r) * 136 + nn] = f2bf(acc[r]);
    } else {
      const int nn = n - 256;
      ushort4 pk;
      pk.x = f2bf(acc[0]); pk.y = f2bf(acc[1]);
      pk.z = f2bf(acc[2]); pk.w = f2bf(acc[3]);
      *(ushort4*)(vs + nn * 72 + tok0) = pk;   // v transposed [ch][tok]
    }
  }
}

__global__ __launch_bounds__(1024, 2)
void swin_fused(const float* __restrict__ x,
                const unsigned short* __restrict__ wqkvT,
                const unsigned short* __restrict__ woutT,
                const float* __restrict__ b_out,
                const float* __restrict__ pe,     // [15][15]
                const float* __restrict__ ulm,    // [64][64]
                const float* __restrict__ lrm,    // [64][64]
                float* __restrict__ out) {
  __shared__ __align__(16) unsigned char smem[SMEM_SZ];
  unsigned short* q_s    = (unsigned short*)(smem + OFF_Q);
  unsigned short* k_s    = (unsigned short*)(smem + OFF_K);
  unsigned short* v_s    = (unsigned short*)(smem + OFF_V);
  unsigned short* S_s    = (unsigned short*)(smem + OFF_S);
  float*          osr_s  = (float*)(smem + OFF_S);          // union with S
  unsigned short* oa_s   = (unsigned short*)(smem + OFF_OA);
  float*          bias_s = (float*)(smem + OFF_BI);

  const int tid  = threadIdx.x;
  const int lane = tid & 63;
  const int wave = tid >> 6;        // 0..15
  const int ln15 = lane & 15;
  const int quad = lane >> 4;
  const int m_sub = quad << 2;

  const int wh = blockIdx.x >> 4, ww = blockIdx.x & 15;

  // attn task: one (h, mt) per wave -- serial depth 1 (R5 shape).
  const int h_a   = wave >> 2;
  const int mt_a  = wave & 3;
  const int tok0a = mt_a * 16 + m_sub;

  // proj task: (n-tile, m-pair) per wave.
  const int nt_p  = wave >> 1;
  const int mtb_p = (wave & 1) * 2;

  // qkv task: fixed mh = wave&1; nt = wave>>1 + {0,8,16} (q,k,v).
  const int mh = wave & 1;
  int rowoff[2];
#pragma unroll
  for (int mi = 0; mi < 2; ++mi) {
    int tok = (mh * 2 + mi) * 16 + ln15;
    int gi = ((wh << 3) + (tok >> 3) + 4) & 127;
    int gj = ((ww << 3) + (tok & 7) + 4) & 127;
    rowoff[mi] = (gi * 128 + gj) * 128;
  }

  // store pass: 2 float4 per thread, fixed addresses.
  const int tokA = tid >> 5, c4 = tid & 31;
  const int tokB = tokA + 32;
  const int giA = ((wh << 3) + (tokA >> 3) + 4) & 127;
  const int gjA = ((ww << 3) + (tokA & 7) + 4) & 127;
  const int giB = ((wh << 3) + (tokB >> 3) + 4) & 127;
  const int gjB = ((ww << 3) + (tokB & 7) + 4) & 127;
  const long offA = (long)(giA * 128 + gjA) * 128 + c4 * 4;
  const long offB = (long)(giB * 128 + gjB) * 128 + c4 * 4;
  const int lA = tokA * 132 + c4 * 4;
  const int lB = tokB * 132 + c4 * 4;

  // ---- prologue: bias table + x(0)->regs->QKV(0) ----
  {
    const bool has_ul = (wh == 15), has_lr = (ww == 15);
#pragma unroll
    for (int it = 0; it < 4; ++it) {
      int t = tid + it * 1024;
      int i = t >> 6, j = t & 63;
      int r0 = (j >> 3) - (i >> 3) + 7;
      int r1 = (j & 7) - (i & 7) + 7;
      float bsum = pe[r0 * 15 + r1];
      if (has_ul) bsum += ulm[t];
      if (has_lr) bsum += lrm[t];
      bias_s[i * 65 + j] = bsum;
    }
  }
  s16x8 xf[2][4];
#pragma unroll
  for (int mi = 0; mi < 2; ++mi)
#pragma unroll
    for (int ks = 0; ks < 4; ++ks) {
      const float* p = x + rowoff[mi] + ks * 32 + quad * 8;
      float4 lo = *(const float4*)p;
      float4 hi = *(const float4*)(p + 4);
      xf[mi][ks] = cvt8(lo, hi);
    }
  qkv_task<0>(wave >> 1,        xf, wqkvT, q_s, k_s, v_s, ln15, quad, m_sub, mh);
  qkv_task<1>((wave >> 1) + 8,  xf, wqkvT, q_s, k_s, v_s, ln15, quad, m_sub, mh);
  qkv_task<2>((wave >> 1) + 16, xf, wqkvT, q_s, k_s, v_s, ln15, quad, m_sub, mh);
  bar_lds();

  for (int b = 0; b < 16; ++b) {
    const bool pf = (b < 15);

    // ---- ph2: attn(b) -- QK^T + bias -> register softmax -> P -> PV ------
    {
      unsigned short* Sh = S_s + h_a * 64 * 72;
      s16x8 qf = *(const s16x8*)(q_s + (mt_a * 16 + ln15) * 136 + h_a * 32 + quad * 8);
      const float scale = 0.17677669529663687f;   // 32^-0.5
      f32x4 sv[4];
#pragma unroll
      for (int nt = 0; nt < 4; ++nt) {
        s16x8 kf = *(const s16x8*)(k_s + (nt * 16 + ln15) * 136 + h_a * 32 + quad * 8);
        f32x4 acc = {0.f, 0.f, 0.f, 0.f};
        acc = mfma16(qf, kf, acc);
        int nn = nt * 16 + ln15;
#pragma unroll
        for (int r = 0; r < 4; ++r)
          sv[nt][r] = acc[r] * scale + bias_s[(tok0a + r) * 65 + nn];
      }
      float rinv[4];
#pragma unroll
      for (int r = 0; r < 4; ++r) {
        float m0 = fmaxf(fmaxf(sv[0][r], sv[1][r]), fmaxf(sv[2][r], sv[3][r]));
        m0 = fmaxf(m0, __shfl_xor(m0, 1));
        m0 = fmaxf(m0, __shfl_xor(m0, 2));
        m0 = fmaxf(m0, __shfl_xor(m0, 4));
        m0 = fmaxf(m0, __shfl_xor(m0, 8));
        float s0 = 0.f;
#pragma unroll
        for (int nt = 0; nt < 4; ++nt) {
          float e = __expf(sv[nt][r] - m0);
          sv[nt][r] = e;
          s0 += e;
        }
        s0 += __shfl_xor(s0, 1);
        s0 += __shfl_xor(s0, 2);
        s0 += __shfl_xor(s0, 4);
        s0 += __shfl_xor(s0, 8);
        rinv[r] = 1.0f / s0;
      }
#pragma unroll
      for (int nt = 0; nt < 4; ++nt) {
        int nn = nt * 16 + ln15;
#pragma unroll
        for (int r = 0; r < 4; ++r)
          Sh[(tok0a + r) * 72 + nn] = f2bf(sv[nt][r] * rinv[r]);
      }
      // same-wave LDS RAW: wave-level drain only (rule 18 fence)
      asm volatile("s_waitcnt lgkmcnt(0)" ::: "memory");
      __builtin_amdgcn_sched_barrier(0);
      s16x8 pfr[2];
#pragma unroll
      for (int ks = 0; ks < 2; ++ks)
        pfr[ks] = *(const s16x8*)(Sh + (mt_a * 16 + ln15) * 72 + ks * 32 + quad * 8);
#pragma unroll
      for (int nt2 = 0; nt2 < 2; ++nt2) {
        f32x4 acc = {0.f, 0.f, 0.f, 0.f};
#pragma unroll
        for (int ks = 0; ks < 2; ++ks) {
          s16x8 vf = *(const s16x8*)(v_s + (h_a * 32 + nt2 * 16 + ln15) * 72 + ks * 32 + quad * 8);
          acc = mfma16(pfr[ks], vf, acc);
        }
        int n = h_a * 32 + nt2 * 16 + ln15;
#pragma unroll
        for (int r = 0; r < 4; ++r)
          oa_s[(tok0a + r) * 136 + n] = f2bf(acc[r]);
      }
    }
    bar_lds();

    // ---- ph5: out-proj(b) oa->osr, interleaved with x(b+1) prefetch ------
    // Raw f32 prefetch regs live ONLY inside this phase (R7 spill lesson):
    // issue 8 -> proj mi=0 -> cvt (frees 32 regs) -> issue 8 -> proj mi=1
    // -> cvt. xf (bf16, 16 regs) is what crosses the barrier.
    {
      const float* xb = x + (long)(b + 1) * BATCH_STRIDE;
      float4 raw[4][2];
      if (pf) {
#pragma unroll
        for (int ks = 0; ks < 4; ++ks) {
          const float* p = xb + rowoff[0] + ks * 32 + quad * 8;
          raw[ks][0] = *(const float4*)p;
          raw[ks][1] = *(const float4*)(p + 4);
        }
      }
      int n = nt_p * 16 + ln15;
      const unsigned short* wp = woutT + n * 128 + quad * 8;
      s16x8 bfr[4];
#pragma unroll
      for (int ks = 0; ks < 4; ++ks) bfr[ks] = *(const s16x8*)(wp + ks * 32);
      float bo = b_out[n];
      // proj mi=0
      {
        int mt = mtb_p;
        s16x8 af[4];
#pragma unroll
        for (int ks = 0; ks < 4; ++ks)
          af[ks] = *(const s16x8*)(oa_s + (mt * 16 + ln15) * 136 + ks * 32 + quad * 8);
        f32x4 acc = {0.f, 0.f, 0.f, 0.f};
#pragma unroll
        for (int ks = 0; ks < 4; ++ks) acc = mfma16(af[ks], bfr[ks], acc);
#pragma unroll
        for (int r = 0; r < 4; ++r)
          osr_s[(mt * 16 + m_sub + r) * 132 + n] = acc[r] + bo;
      }
      if (pf) {
#pragma unroll
        for (int ks = 0; ks < 4; ++ks) xf[0][ks] = cvt8(raw[ks][0], raw[ks][1]);
#pragma unroll
        for (int ks = 0; ks < 4; ++ks) {
          const float* p = xb + rowoff[1] + ks * 32 + quad * 8;
          raw[ks][0] = *(const float4*)p;
          raw[ks][1] = *(const float4*)(p + 4);
        }
      }
      // proj mi=1
      {
        int mt = mtb_p + 1;
        s16x8 af[4];
#pragma unroll
        for (int ks = 0; ks < 4; ++ks)
          af[ks] = *(const s16x8*)(oa_s + (mt * 16 + ln15) * 136 + ks * 32 + quad * 8);
        f32x4 acc = {0.f, 0.f, 0.f, 0.f};
#pragma unroll
        for (int ks = 0; ks < 4; ++ks) acc = mfma16(af[ks], bfr[ks], acc);
#pragma unroll
        for (int r = 0; r < 4; ++r)
          osr_s[(mt * 16 + m_sub + r) * 132 + n] = acc[r] + bo;
      }
      if (pf) {
#pragma unroll
        for (int ks = 0; ks < 4; ++ks) xf[1][ks] = cvt8(raw[ks][0], raw[ks][1]);
      }
    }
    bar_lds();

    // ---- ph6: coalesced stores(b) + QKV(b+1) from registers --------------
    {
      float* outb = out + (long)b * BATCH_STRIDE;
      float4 o0 = *(const float4*)(osr_s + lA);
      *(float4*)(outb + offA) = o0;
      float4 o1 = *(const float4*)(osr_s + lB);
      *(float4*)(outb + offB) = o1;
    }
    if (pf) {
      qkv_task<0>(wave >> 1,        xf, wqkvT, q_s, k_s, v_s, ln15, quad, m_sub, mh);
      qkv_task<1>((wave >> 1) + 8,  xf, wqkvT, q_s, k_s, v_s, ln15, quad, m_sub, mh);
      qkv_task<2>((wave >> 1) + 16, xf, wqkvT, q_s, k_s, v_s, ln15, quad, m_sub, mh);
    }
    bar_lds();
  }
}

extern "C" void kernel_launch(void* const* d_in, const int* in_sizes, int n_in,
                              void* d_out, int out_size, void* d_ws, size_t ws_size,
                              hipStream_t stream) {
  const float* x    = (const float*)d_in[0];
  const float* wqkv = (const float*)d_in[1];
  const float* wout = (const float*)d_in[2];
  const float* bout = (const float*)d_in[3];
  const float* pe   = (const float*)d_in[4];
  const float* ulm  = (const float*)d_in[5];
  const float* lrm  = (const float*)d_in[6];

  unsigned short* wqkvT = (unsigned short*)d_ws;           // 384*128 bf16
  unsigned short* woutT = wqkvT + 384 * 128;               // 128*128 bf16

  prep_weights<<<(384 * 128 + 128 * 128) / 256, 256, 0, stream>>>(wqkv, wout, wqkvT, woutT);
  swin_fused<<<256, 1024, 0, stream>>>(x, wqkvT, woutT, bout, pe, ulm, lrm,
                                       (float*)d_out);
}

// Round 11
// 285.956 us; speedup vs baseline: 2.0890x; 1.6571x over previous
//
#include <hip/hip_runtime.h>

// Swin window attention, fully fused, persistent blocks (1 block/CU, 256
// blocks, 16-batch loop per block).
//
// R9 = R5 (162us session best) + attention-phase micro-surgery ONLY.
// R6/R7/R8 post-mortems (all reverted): R6 role-split halved waves on the
// latency-critical attn (269us); R7 held 64 f32 prefetch regs across a phase
// under the 64-VGPR cap -> scratch spill, hbm 1.25GB (449us); R8 register-
// staged x that is SHARED across waves -> 8x duplicated loads+cvt (320us).
// Structure, barriers, prefetch, ph1/ph5/ph6 are byte-identical to R5.
//
// R9 ph2 changes (T12-style swapped QK^T):
//  - compute mfma(K,Q) instead of mfma(Q,K): D[kt][qt], so each lane owns
//    one full q-row of P in registers (16 values in-lane).
//    Softmax row-reduce: 15 in-lane fmax + 2 shfl_xor (was 4 rows x 8 shfl
//    = 32), one 1/s0 divide (was 4), sum tree in-lane (was 4x shfl chains).
//  - exp2 domain: bias table pre-multiplied by log2(e), scale' = scale*log2e
//    -> direct v_exp_f32 via __builtin_amdgcn_exp2f, deletes 16 v_mul.
//  - P-store vectorized: 4x ushort4 (was 16x u16); bias loads vectorized:
//    4x float4 (bias repadded [64][68] f32 for 16B alignment).
//  - native bf16 casts everywhere (R8-verified bit-identical absmax).
// PV unchanged (A-frag read layout identical).
//
// MFMA 16x16x32 bf16 fragment layouts (HW-verified per guide m89/m91/m120):
//   A[m][k]: m = lane&15, k = (lane>>4)*8 + j   (8 contiguous bf16 = 16B)
//   B[k][n]: n = lane&15, k = (lane>>4)*8 + j
//   D[m][n]: n = lane&15, m = (lane>>4)*4 + reg
// Swapped QK^T: A=K-frag, B=Q-frag -> D[m=kt-local][n=qt-local]; lane
// (ln15,quad) holds S[kt=nt*16+quad*4+r][qt=mt*16+ln15] over nt -- one
// q-column... i.e. one q-row of P^T per lane, reduced in-lane + 2 quad-shfls.

typedef __bf16 bf16x8 __attribute__((ext_vector_type(8)));
typedef short  s16x8  __attribute__((ext_vector_type(8)));
typedef float  f32x4  __attribute__((ext_vector_type(4)));

static __device__ __forceinline__ unsigned short f2bf(float f) {
  __bf16 h = (__bf16)f;                      // RNE; compiler emits cvt_pk pairs
  return __builtin_bit_cast(unsigned short, h);
}
static __device__ __forceinline__ f32x4 mfma16(s16x8 a, s16x8 b, f32x4 c) {
  return __builtin_amdgcn_mfma_f32_16x16x32_bf16(
      __builtin_bit_cast(bf16x8, a), __builtin_bit_cast(bf16x8, b), c, 0, 0, 0);
}
// LDS-only barrier: orders ds ops across waves without draining vmcnt.
static __device__ __forceinline__ void bar_lds() {
  __builtin_amdgcn_sched_barrier(0);
  asm volatile("s_waitcnt lgkmcnt(0)" ::: "memory");
  __builtin_amdgcn_s_barrier();
  __builtin_amdgcn_sched_barrier(0);
}

// ---------------- prep: transpose + bf16-cast weights into workspace --------
__global__ void prep_weights(const float* __restrict__ wqkv,
                             const float* __restrict__ wout,
                             unsigned short* __restrict__ wqkvT,
                             unsigned short* __restrict__ woutT) {
  int idx = blockIdx.x * blockDim.x + threadIdx.x;
  const int total1 = 384 * 128;
  if (idx < total1) {
    int n = idx >> 7, k = idx & 127;
    wqkvT[idx] = f2bf(wqkv[k * 384 + n]);
  } else {
    int i2 = idx - total1;
    int n = i2 >> 7, k = i2 & 127;
    woutT[i2] = f2bf(wout[k * 128 + n]);
  }
}

// ---------------- LDS layout ------------------------------------------------
//   xs   [64][136] bf16   17408  @ 0        (staged x window, batch-cycled)
//   q    [64][136] bf16   17408  @ 17408
//   k    [64][136] bf16   17408  @ 34816
//   v    [128][72] bf16   18432  @ 52224    (v transposed: [ch][tok])
//   S    [4][64][72] bf16 36864  @ 70656    (P in ph2; f32 osr[64][132] union)
//   oa   [64][136] bf16   17408  @ 107520
//   bias [64][68] f32     17408  @ 124928   (pre-scaled by log2e; stride 68
//                                            = 0 mod 4 words for float4 loads)
#define OFF_XS  0
#define OFF_Q   17408
#define OFF_K   34816
#define OFF_V   52224
#define OFF_S   70656
#define OFF_OA  107520
#define OFF_BI  124928
#define SMEM_SZ 142336

#define BATCH_STRIDE (128 * 128 * 128)   // floats per batch image

__global__ __launch_bounds__(1024, 4)
void swin_fused(const float* __restrict__ x,
                const unsigned short* __restrict__ wqkvT,
                const unsigned short* __restrict__ woutT,
                const float* __restrict__ b_out,
                const float* __restrict__ pe,     // [15][15]
                const float* __restrict__ ulm,    // [64][64]
                const float* __restrict__ lrm,    // [64][64]
                float* __restrict__ out) {
  __shared__ __align__(16) unsigned char smem[SMEM_SZ];
  unsigned short* xs_s   = (unsigned short*)(smem + OFF_XS);
  unsigned short* q_s    = (unsigned short*)(smem + OFF_Q);
  unsigned short* k_s    = (unsigned short*)(smem + OFF_K);
  unsigned short* v_s    = (unsigned short*)(smem + OFF_V);
  unsigned short* S_s    = (unsigned short*)(smem + OFF_S);
  float*          osr_s  = (float*)(smem + OFF_S);          // union with S
  unsigned short* oa_s   = (unsigned short*)(smem + OFF_OA);
  float*          bias_s = (float*)(smem + OFF_BI);

  const int tid  = threadIdx.x;
  const int lane = tid & 63;
  const int wave = tid >> 6;       // 0..15
  const int ln15 = lane & 15;
  const int quad = lane >> 4;
  const int m_sub = quad << 2;

  const int wh = blockIdx.x >> 4, ww = blockIdx.x & 15;

  // per-thread x/out addresses: 2 token-quarter-rows per thread, constant
  // across batches (only the batch base advances).
  const int tokA = tid >> 5, c4 = tid & 31;    // 32 float4 per 128-ch token row
  const int tokB = tokA + 32;
  const int giA = ((wh << 3) + (tokA >> 3) + 4) & 127;
  const int gjA = ((ww << 3) + (tokA & 7) + 4) & 127;
  const int giB = ((wh << 3) + (tokB >> 3) + 4) & 127;
  const int gjB = ((ww << 3) + (tokB & 7) + 4) & 127;
  const long offA = (long)(giA * 128 + gjA) * 128 + c4 * 4;
  const long offB = (long)(giB * 128 + gjB) * 128 + c4 * 4;
  const float* xA = x + offA;
  const float* xB = x + offB;

  // ---- prologue: stage batch-0 x window + build bias table (once) ----
  {
    float4 a0 = *(const float4*)xA;
    float4 b0 = *(const float4*)xB;
    ushort4 pk;
    pk.x = f2bf(a0.x); pk.y = f2bf(a0.y); pk.z = f2bf(a0.z); pk.w = f2bf(a0.w);
    *(ushort4*)(xs_s + tokA * 136 + c4 * 4) = pk;
    pk.x = f2bf(b0.x); pk.y = f2bf(b0.y); pk.z = f2bf(b0.z); pk.w = f2bf(b0.w);
    *(ushort4*)(xs_s + tokB * 136 + c4 * 4) = pk;

    const bool has_ul = (wh == 15), has_lr = (ww == 15);
    const float log2e = 1.4426950408889634f;
#pragma unroll
    for (int it = 0; it < 4; ++it) {
      int t = tid + it * 1024;             // 4096 bias entries
      int i = t >> 6, j = t & 63;
      int r0 = (j >> 3) - (i >> 3) + 7;
      int r1 = (j & 7) - (i & 7) + 7;
      float bsum = pe[r0 * 15 + r1];
      if (has_ul) bsum += ulm[t];
      if (has_lr) bsum += lrm[t];
      bias_s[i * 68 + j] = bsum * log2e;   // log2 domain for exp2 softmax
    }
  }
  __syncthreads();

  for (int b = 0; b < 16; ++b) {
    // ---- phase 1: QKV GEMM (M=64,K=128,N=384) + prefetch issue ----------
    float4 pfA, pfB;
    const bool pf = (b < 15);
    if (pf) {
      pfA = *(const float4*)(xA + (b + 1) * BATCH_STRIDE);
      pfB = *(const float4*)(xB + (b + 1) * BATCH_STRIDE);
    }
    // 48 half-tiles (24 n-tiles x 2 m-halves) over 16 waves = 3 tasks each.
#pragma unroll
    for (int it = 0; it < 3; ++it) {
      int t  = wave + (it << 4);
      int nt = t >> 1, mh = t & 1;
      int n0 = nt << 4;
      int n  = n0 + ln15;
      const unsigned short* wp = wqkvT + n * 128 + quad * 8;
      s16x8 bfr[4];
#pragma unroll
      for (int ks = 0; ks < 4; ++ks) bfr[ks] = *(const s16x8*)(wp + ks * 32);
#pragma unroll
      for (int mi = 0; mi < 2; ++mi) {
        int mt = mh * 2 + mi;
        f32x4 acc = {0.f, 0.f, 0.f, 0.f};
#pragma unroll
        for (int ks = 0; ks < 4; ++ks) {
          s16x8 a = *(const s16x8*)(xs_s + (mt * 16 + ln15) * 136 + ks * 32 + quad * 8);
          acc = mfma16(a, bfr[ks], acc);
        }
        int tok0 = mt * 16 + m_sub;
        if (n0 < 128) {               // q
#pragma unroll
          for (int r = 0; r < 4; ++r) q_s[(tok0 + r) * 136 + n] = f2bf(acc[r]);
        } else if (n0 < 256) {        // k
          int nn = n - 128;
#pragma unroll
          for (int r = 0; r < 4; ++r) k_s[(tok0 + r) * 136 + nn] = f2bf(acc[r]);
        } else {                      // v (transposed [ch][tok])
          int nn = n - 256;
          ushort4 pk;
          pk.x = f2bf(acc[0]); pk.y = f2bf(acc[1]);
          pk.z = f2bf(acc[2]); pk.w = f2bf(acc[3]);
          *(ushort4*)(v_s + nn * 72 + tok0) = pk;
        }
      }
    }
    bar_lds();

    // ---- phase 2 (fused): swapped QK^T -> in-lane softmax -> P -> PV -----
    {
      const int h  = wave >> 2;
      const int mt = wave & 3;
      unsigned short* Sh = S_s + h * 64 * 72;
      // Q-fragment as B-operand; lane's q-token = mt*16 + ln15.
      s16x8 qf = *(const s16x8*)(q_s + (mt * 16 + ln15) * 136 + h * 32 + quad * 8);
      // scale' = 32^-0.5 * log2(e)  (log2-domain scores for exp2)
      const float scale2 = 0.17677669529663687f * 1.4426950408889634f;
      const float* brow = bias_s + (mt * 16 + ln15) * 68;   // bias'[qt][*]
      f32x4 sv[4];
#pragma unroll
      for (int nt = 0; nt < 4; ++nt) {
        s16x8 kf = *(const s16x8*)(k_s + (nt * 16 + ln15) * 136 + h * 32 + quad * 8);
        f32x4 acc = {0.f, 0.f, 0.f, 0.f};
        acc = mfma16(kf, qf, acc);              // swapped: D[kt-local][qt-local]
        float4 bv = *(const float4*)(brow + nt * 16 + quad * 4);
#pragma unroll
        for (int r = 0; r < 4; ++r)
          sv[nt][r] = acc[r] * scale2 + ((const float*)&bv)[r];
      }

      // write next batch's prefetched x window (xs dead since ph1-end bar;
      // compiler inserts the vmcnt wait for pfA/pfB right before use)
      if (pf) {
        ushort4 pk;
        pk.x = f2bf(pfA.x); pk.y = f2bf(pfA.y); pk.z = f2bf(pfA.z); pk.w = f2bf(pfA.w);
        *(ushort4*)(xs_s + tokA * 136 + c4 * 4) = pk;
        pk.x = f2bf(pfB.x); pk.y = f2bf(pfB.y); pk.z = f2bf(pfB.z); pk.w = f2bf(pfB.w);
        *(ushort4*)(xs_s + tokB * 136 + c4 * 4) = pk;
      }

      // in-lane softmax over this lane's full q-row (16 values) + 2 shfls
      // across quads (lane^16, lane^32 keep ln15 -> same q-token).
      float mnt[4];
#pragma unroll
      for (int nt = 0; nt < 4; ++nt)
        mnt[nt] = fmaxf(fmaxf(sv[nt][0], sv[nt][1]), fmaxf(sv[nt][2], sv[nt][3]));
      float m0 = fmaxf(fmaxf(mnt[0], mnt[1]), fmaxf(mnt[2], mnt[3]));
      m0 = fmaxf(m0, __shfl_xor(m0, 16));
      m0 = fmaxf(m0, __shfl_xor(m0, 32));
      float psum[4];
#pragma unroll
      for (int nt = 0; nt < 4; ++nt) {
#pragma unroll
        for (int r = 0; r < 4; ++r)
          sv[nt][r] = __builtin_amdgcn_exp2f(sv[nt][r] - m0);
        psum[nt] = (sv[nt][0] + sv[nt][1]) + (sv[nt][2] + sv[nt][3]);
      }
      float s0 = (psum[0] + psum[1]) + (psum[2] + psum[3]);
      s0 += __shfl_xor(s0, 16);
      s0 += __shfl_xor(s0, 32);
      const float rinv = 1.0f / s0;
      // store normalized P rows [mt*16, mt*16+16): lane's q-row at
      // Sh[qt-local][kt], vectorized ushort4 (kt = nt*16 + quad*4 + r).
#pragma unroll
      for (int nt = 0; nt < 4; ++nt) {
        ushort4 pk;
        pk.x = f2bf(sv[nt][0] * rinv);
        pk.y = f2bf(sv[nt][1] * rinv);
        pk.z = f2bf(sv[nt][2] * rinv);
        pk.w = f2bf(sv[nt][3] * rinv);
        *(ushort4*)(Sh + (mt * 16 + ln15) * 72 + nt * 16 + quad * 4) = pk;
      }
      // same-wave LDS RAW: wave-level drain, no block barrier needed
      asm volatile("s_waitcnt lgkmcnt(0)" ::: "memory");
      __builtin_amdgcn_sched_barrier(0);

      // PV (M=64,K=64,N=32 for this head) -- unchanged from R5
      const int tok0 = mt * 16 + m_sub;
      s16x8 pfr[2];
#pragma unroll
      for (int ks = 0; ks < 2; ++ks)
        pfr[ks] = *(const s16x8*)(Sh + (mt * 16 + ln15) * 72 + ks * 32 + quad * 8);
#pragma unroll
      for (int nt = 0; nt < 2; ++nt) {
        f32x4 acc = {0.f, 0.f, 0.f, 0.f};
#pragma unroll
        for (int ks = 0; ks < 2; ++ks) {
          s16x8 vf = *(const s16x8*)(v_s + (h * 32 + nt * 16 + ln15) * 72 + ks * 32 + quad * 8);
          acc = mfma16(pfr[ks], vf, acc);
        }
        int n = h * 32 + nt * 16 + ln15;
#pragma unroll
        for (int r = 0; r < 4; ++r)
          oa_s[(tok0 + r) * 136 + n] = f2bf(acc[r]);
      }
    }
    bar_lds();

    // ---- phase 5: out proj (M=64,K=128,N=128) -> stage f32 rows to LDS ---
    {
      const int nt  = wave >> 1;           // 0..7
      const int mtb = (wave & 1) * 2;      // {0,2}
      int n = nt * 16 + ln15;
      s16x8 bfr[4];
      const unsigned short* wp = woutT + n * 128 + quad * 8;
#pragma unroll
      for (int ks = 0; ks < 4; ++ks) bfr[ks] = *(const s16x8*)(wp + ks * 32);
      float bo = b_out[n];
#pragma unroll
      for (int mi = 0; mi < 2; ++mi) {
        int mt = mtb + mi;
        f32x4 acc = {0.f, 0.f, 0.f, 0.f};
#pragma unroll
        for (int ks = 0; ks < 4; ++ks) {
          s16x8 a = *(const s16x8*)(oa_s + (mt * 16 + ln15) * 136 + ks * 32 + quad * 8);
          acc = mfma16(a, bfr[ks], acc);
        }
        int tok0 = mt * 16 + m_sub;
#pragma unroll
        for (int r = 0; r < 4; ++r)
          osr_s[(tok0 + r) * 132 + n] = acc[r] + bo;
      }
    }
    bar_lds();

    // ---- phase 6: coalesced store -- full 512B token rows as float4 ------
    {
      float* outb = out + (long)b * BATCH_STRIDE;
      float4 o0 = *(const float4*)(osr_s + tokA * 132 + c4 * 4);
      *(float4*)(outb + offA) = o0;
      float4 o1 = *(const float4*)(osr_s + tokB * 132 + c4 * 4);
      *(float4*)(outb + offB) = o1;
    }
    // no barrier here: next ph1 touches xs/q/k/v (disjoint from osr); the
    // ph1-end barrier orders these ds_reads against next ph2's S writes.
  }
}

extern "C" void kernel_launch(void* const* d_in, const int* in_sizes, int n_in,
                              void* d_out, int out_size, void* d_ws, size_t ws_size,
                              hipStream_t stream) {
  const float* x    = (const float*)d_in[0];
  const float* wqkv = (const float*)d_in[1];
  const float* wout = (const float*)d_in[2];
  const float* bout = (const float*)d_in[3];
  const float* pe   = (const float*)d_in[4];
  const float* ulm  = (const float*)d_in[5];
  const float* lrm  = (const float*)d_in[6];

  unsigned short* wqkvT = (unsigned short*)d_ws;           // 384*128 bf16
  unsigned short* woutT = wqkvT + 384 * 128;               // 128*128 bf16

  prep_weights<<<(384 * 128 + 128 * 128) / 256, 256, 0, stream>>>(wqkv, wout, wqkvT, woutT);
  swin_fused<<<16 * 16, 1024, 0, stream>>>(x, wqkvT, woutT, bout, pe, ulm, lrm,
                                           (float*)d_out);
}